// Round 5
// baseline (573.310 us; speedup 1.0000x reference)
//
#include <hip/hip_runtime.h>
#include <hip/hip_bf16.h>

// ScaledDotProductAttention: B=16, N=2048, D=64. q/k/v fp32, mask int32,
// out fp32. scores = q@k^T/sqrt(N); masked -> -1000; softmax over dim=1
// (COLUMN-wise over n); out = attn @ v.
// out[n,d] = sum_m exp(s[n,m])*[!mask] * (v[m,d]/colsum[m]).
//
// R5: single raw-mask sweep fused into colsum (ballot -> transposed bitmask),
// leaner attn_out (broadcast uint2 bit loads, __syncthreads instead of
// scheduler-pinning asm fences), 5 dispatches:
//   1. cvt:         q,k fp32 -> bf16
//   2. colsum_pack: csp[z][b][m] partials + bitsT[b][m/16][n] (ushort words)
//   3. vprep:       vt[b][d][m] = bf16(v[b][m][d] / sum_z csp)
//   4. attn_out:    recompute P, LDS C->A relayout, PV MFMA; MCH=2 partials
//   5. reduce_out:  sum the 2 partials

#define B_ 16
#define N_ 2048
#define D_ 64
#define SCALE 0.022097086912079608f  // 1/sqrt(2048)
#define MCH 2                        // m-chunks for attn_out
#define NCH 4                        // n-chunks for colsum

typedef __attribute__((ext_vector_type(8))) short bf16x8;
typedef __attribute__((ext_vector_type(4))) float f32x4;

static __device__ __forceinline__ short f2bf(float x) {
  unsigned u = __float_as_uint(x);
  return (short)((u + 0x7FFF + ((u >> 16) & 1)) >> 16);
}

static __device__ __forceinline__ bf16x8 load8(const short* p) {
  return *reinterpret_cast<const bf16x8*>(p);
}

static __device__ __forceinline__ bf16x8 load8f(const float* p) {
  const f32x4 a = *reinterpret_cast<const f32x4*>(p);
  const f32x4 b = *reinterpret_cast<const f32x4*>(p + 4);
  bf16x8 r;
  r[0] = f2bf(a[0]); r[1] = f2bf(a[1]); r[2] = f2bf(a[2]); r[3] = f2bf(a[3]);
  r[4] = f2bf(b[0]); r[5] = f2bf(b[1]); r[6] = f2bf(b[2]); r[7] = f2bf(b[3]);
  return r;
}

// ---------------- 1. fp32 -> bf16 convert (q: y=0, k: y=1) ----------------
__global__ __launch_bounds__(256) void cvt_bf16(const float* __restrict__ q,
                                                const float* __restrict__ k,
                                                short* __restrict__ qb,
                                                short* __restrict__ kb) {
  const size_t i = ((size_t)blockIdx.x * 256 + threadIdx.x) * 8;
  const float* src = blockIdx.y ? k : q;
  short* dst = blockIdx.y ? kb : qb;
  *reinterpret_cast<bf16x8*>(dst + i) = load8f(src + i);
}

// ------- 2. colsum partials + bitmask pack (single raw-mask sweep) -------
// grid (B, N/128, NCH); 4 waves/block; wave owns 32 m-cols, 512 n-rows.
// Covers every (b,n,m) exactly once -> mask read exactly once device-wide.
// bitsT layout: ushort bitsT[B][128][2048]; bitsT[b][wc][n] bit j =
// mask[b][n][wc*16+j]. Ballot: lane = lhi*16+l15, element (n=n0+lhi*4+r,
// m=m0+cg*16+l15) -> ushort g of ballot covers row n0+4g+r, cols m0+cg*16+.
__global__ __launch_bounds__(256) void colsum_pack(
    const short* __restrict__ qb, const short* __restrict__ kb,
    const int* __restrict__ mask, unsigned short* __restrict__ bitsT,
    float* __restrict__ csp) {
  const int b = blockIdx.x;
  const int wave = threadIdx.x >> 6;
  const int lane = threadIdx.x & 63;
  const int l15 = lane & 15;
  const int lhi = lane >> 4;
  const int m0 = blockIdx.y * 128 + wave * 32;
  const int nbase = blockIdx.z * (N_ / NCH);

  const short* qbb = qb + (size_t)b * N_ * D_;
  const short* kbb = kb + (size_t)b * N_ * D_;
  const int* maskb = mask + (size_t)b * N_ * N_;
  unsigned short* bitsTb = bitsT + (size_t)b * 128 * N_;

  bf16x8 kf[2][2];
#pragma unroll
  for (int cg = 0; cg < 2; ++cg) {
    kf[cg][0] = load8(kbb + (m0 + cg * 16 + l15) * D_ + lhi * 8);
    kf[cg][1] = load8(kbb + (m0 + cg * 16 + l15) * D_ + 32 + lhi * 8);
  }

  float part[2] = {0.f, 0.f};
  for (int n0 = nbase; n0 < nbase + N_ / NCH; n0 += 16) {
    const bf16x8 qf0 = load8(qbb + (n0 + l15) * D_ + lhi * 8);
    const bf16x8 qf1 = load8(qbb + (n0 + l15) * D_ + 32 + lhi * 8);
#pragma unroll
    for (int cg = 0; cg < 2; ++cg) {
      f32x4 acc = {0.f, 0.f, 0.f, 0.f};
      acc = __builtin_amdgcn_mfma_f32_16x16x32_bf16(qf0, kf[cg][0], acc, 0, 0, 0);
      acc = __builtin_amdgcn_mfma_f32_16x16x32_bf16(qf1, kf[cg][1], acc, 0, 0, 0);
      const int wc = (m0 >> 4) + cg;
#pragma unroll
      for (int r = 0; r < 4; ++r) {
        const int n = n0 + lhi * 4 + r;
        const int msk = maskb[(size_t)n * N_ + m0 + cg * 16 + l15];
        const unsigned long long bal = __ballot(msk != 0);
        if (l15 == 0)
          bitsTb[(size_t)wc * N_ + n0 + 4 * lhi + r] =
              (unsigned short)(bal >> (lhi * 16));
        part[cg] += msk ? 0.f : __expf(acc[r] * SCALE);
      }
    }
  }
#pragma unroll
  for (int cg = 0; cg < 2; ++cg) {
    float p = part[cg];
    p += __shfl_xor(p, 16, 64);
    p += __shfl_xor(p, 32, 64);
    if (lane < 16)
      csp[(size_t)blockIdx.z * B_ * N_ + (size_t)b * N_ + m0 + cg * 16 + l15] =
          p;
  }
}

// ------- 3. vt[b][d][m] = bf16(v[b][m][d] / sum_z csp[z][b][m]) -------
__global__ __launch_bounds__(256) void vprep_kernel(
    const float* __restrict__ v, const float* __restrict__ csp,
    short* __restrict__ vt) {
  const int b = blockIdx.x;
  const int m0 = blockIdx.y * 64;
  const int tid = threadIdx.x;
  __shared__ float lds[64][65];

  const float* vb = v + (size_t)b * N_ * D_;
#pragma unroll
  for (int pass = 0; pass < 4; ++pass) {
    const int mloc = pass * 16 + (tid >> 4);
    const int d4 = (tid & 15) * 4;
    const f32x4 x = *reinterpret_cast<const f32x4*>(vb + (m0 + mloc) * D_ + d4);
    float cs = 0.f;
#pragma unroll
    for (int z = 0; z < NCH; ++z)
      cs += csp[(size_t)z * B_ * N_ + (size_t)b * N_ + m0 + mloc];
    const float ic = 1.0f / cs;
    lds[mloc][d4 + 0] = x[0] * ic;
    lds[mloc][d4 + 1] = x[1] * ic;
    lds[mloc][d4 + 2] = x[2] * ic;
    lds[mloc][d4 + 3] = x[3] * ic;
  }
  __syncthreads();
  const int d = tid >> 2;
  const int seg = tid & 3;
  bf16x8 o0, o1;
#pragma unroll
  for (int i = 0; i < 8; ++i) o0[i] = f2bf(lds[seg * 16 + i][d]);
#pragma unroll
  for (int i = 0; i < 8; ++i) o1[i] = f2bf(lds[seg * 16 + 8 + i][d]);
  short* dst = vt + (size_t)b * D_ * N_ + (size_t)d * N_ + m0 + seg * 16;
  *reinterpret_cast<bf16x8*>(dst) = o0;
  *reinterpret_cast<bf16x8*>(dst + 8) = o1;
}

// ------- 4. partial out: outp[z] = P(:, mchunk z) @ Vt(mchunk z, :) -------
// grid (B, N/64, MCH); 4 waves/block, 16 n-rows per wave, 1024 m per block.
__global__ __launch_bounds__(256) void attn_out_kernel(
    const short* __restrict__ qb, const short* __restrict__ kb,
    const short* __restrict__ vt, const unsigned short* __restrict__ bitsT,
    float* __restrict__ outp) {
  const int b = blockIdx.x;
  const int wave = threadIdx.x >> 6;
  const int lane = threadIdx.x & 63;
  const int l15 = lane & 15;
  const int lhi = lane >> 4;
  const int n0 = blockIdx.y * 64 + wave * 16;
  const int mbase = blockIdx.z * (N_ / MCH);

  const short* qbb = qb + (size_t)b * N_ * D_;
  const short* kbb = kb + (size_t)b * N_ * D_;
  const short* vtb = vt + (size_t)b * D_ * N_;
  const unsigned short* bitsTb = bitsT + (size_t)b * 128 * N_;

  const bf16x8 qf0 = load8(qbb + (n0 + l15) * D_ + lhi * 8);
  const bf16x8 qf1 = load8(qbb + (n0 + l15) * D_ + 32 + lhi * 8);

  __shared__ __align__(16) short pbuf[4][16][32];

  f32x4 oacc[4];
#pragma unroll
  for (int d = 0; d < 4; ++d) oacc[d] = (f32x4){0.f, 0.f, 0.f, 0.f};

  for (int m0 = mbase; m0 < mbase + N_ / MCH; m0 += 32) {
#pragma unroll
    for (int cg = 0; cg < 2; ++cg) {
      const int mc = m0 + cg * 16;
      const bf16x8 kf0 = load8(kbb + (mc + l15) * D_ + lhi * 8);
      const bf16x8 kf1 = load8(kbb + (mc + l15) * D_ + 32 + lhi * 8);
      // bits for rows n0+lhi*4+{0..3}, wordcol mc/16: one broadcast uint2
      // (ushort4: rows lhi*4 + 0..3), 8B-aligned (n0%16==0, lhi*4 shorts).
      const uint2 u2 = *reinterpret_cast<const uint2*>(
          bitsTb + (size_t)((mc) >> 4) * N_ + n0 + lhi * 4);
      f32x4 acc = {0.f, 0.f, 0.f, 0.f};
      acc = __builtin_amdgcn_mfma_f32_16x16x32_bf16(qf0, kf0, acc, 0, 0, 0);
      acc = __builtin_amdgcn_mfma_f32_16x16x32_bf16(qf1, kf1, acc, 0, 0, 0);
#pragma unroll
      for (int r = 0; r < 4; ++r) {
        const unsigned half = (r < 2 ? u2.x : u2.y) >> ((r & 1) * 16);
        const unsigned bit = (half >> l15) & 1u;
        const float p = bit ? 0.f : __expf(acc[r] * SCALE);
        pbuf[wave][lhi * 4 + r][cg * 16 + l15] = f2bf(p);
      }
    }
    __syncthreads();
    // A-fragment of PV: A[n=l15][mk=lhi*8+j] -> contiguous 16B in pbuf.
    const bf16x8 pa =
        *reinterpret_cast<const bf16x8*>(&pbuf[wave][l15][lhi * 8]);
#pragma unroll
    for (int dsub = 0; dsub < 4; ++dsub) {
      const bf16x8 vf =
          load8(vtb + (size_t)(dsub * 16 + l15) * N_ + m0 + lhi * 8);
      oacc[dsub] =
          __builtin_amdgcn_mfma_f32_16x16x32_bf16(pa, vf, oacc[dsub], 0, 0, 0);
    }
    __syncthreads();
  }

  float* dst = outp + (size_t)blockIdx.z * B_ * N_ * D_ + (size_t)b * N_ * D_;
#pragma unroll
  for (int dsub = 0; dsub < 4; ++dsub)
#pragma unroll
    for (int r = 0; r < 4; ++r)
      dst[(size_t)(n0 + lhi * 4 + r) * D_ + dsub * 16 + l15] = oacc[dsub][r];
}

// ---------------- 5. reduce the MCH partial outputs ----------------
__global__ __launch_bounds__(256) void reduce_out(const float* __restrict__ outp,
                                                  float* __restrict__ out) {
  const size_t i = ((size_t)blockIdx.x * 256 + threadIdx.x) * 4;
  f32x4 s = *reinterpret_cast<const f32x4*>(outp + i);
#pragma unroll
  for (int z = 1; z < MCH; ++z) {
    const f32x4 x =
        *reinterpret_cast<const f32x4*>(outp + (size_t)z * B_ * N_ * D_ + i);
    s[0] += x[0]; s[1] += x[1]; s[2] += x[2]; s[3] += x[3];
  }
  *reinterpret_cast<f32x4*>(out + i) = s;
}

// ================= R2 fallback (small-workspace path), verified ============
__global__ __launch_bounds__(256) void colsum_fb(
    const float* __restrict__ q, const float* __restrict__ k,
    const int* __restrict__ mask, float* __restrict__ colsum) {
  const int b = blockIdx.x;
  const int wave = threadIdx.x >> 6;
  const int lane = threadIdx.x & 63;
  const int l15 = lane & 15;
  const int lhi = lane >> 4;
  const int m0 = blockIdx.y * 64 + wave * 16;
  const float* qbp = q + (size_t)b * N_ * D_;
  const float* kbp = k + (size_t)b * N_ * D_;
  const int* maskb = mask + (size_t)b * N_ * N_;
  const bf16x8 kf0 = load8f(kbp + (m0 + l15) * D_ + lhi * 8);
  const bf16x8 kf1 = load8f(kbp + (m0 + l15) * D_ + 32 + lhi * 8);
  float partial = 0.f;
  for (int n0 = 0; n0 < N_; n0 += 16) {
    bf16x8 qf0 = load8f(qbp + (n0 + l15) * D_ + lhi * 8);
    bf16x8 qf1 = load8f(qbp + (n0 + l15) * D_ + 32 + lhi * 8);
    f32x4 acc = {0.f, 0.f, 0.f, 0.f};
    acc = __builtin_amdgcn_mfma_f32_16x16x32_bf16(qf0, kf0, acc, 0, 0, 0);
    acc = __builtin_amdgcn_mfma_f32_16x16x32_bf16(qf1, kf1, acc, 0, 0, 0);
#pragma unroll
    for (int r = 0; r < 4; ++r) {
      const int n = n0 + lhi * 4 + r;
      partial +=
          maskb[(size_t)n * N_ + m0 + l15] ? 0.f : __expf(acc[r] * SCALE);
    }
  }
  partial += __shfl_xor(partial, 16, 64);
  partial += __shfl_xor(partial, 32, 64);
  if (lane < 16) colsum[(size_t)b * N_ + m0 + l15] = partial;
}

__global__ __launch_bounds__(256) void attn_out_fb(
    const float* __restrict__ q, const float* __restrict__ k,
    const float* __restrict__ v, const int* __restrict__ mask,
    const float* __restrict__ colsum, float* __restrict__ out) {
  const int b = blockIdx.x;
  const int wave = threadIdx.x >> 6;
  const int lane = threadIdx.x & 63;
  const int l15 = lane & 15;
  const int lhi = lane >> 4;
  const int n0 = blockIdx.y * 64 + wave * 16;
  const float* qbp = q + (size_t)b * N_ * D_;
  const float* kbp = k + (size_t)b * N_ * D_;
  const float* vbp = v + (size_t)b * N_ * D_;
  const int* maskb = mask + (size_t)b * N_ * N_;
  const float* csb = colsum + (size_t)b * N_;
  const bf16x8 qf0 = load8f(qbp + (n0 + l15) * D_ + lhi * 8);
  const bf16x8 qf1 = load8f(qbp + (n0 + l15) * D_ + 32 + lhi * 8);
  __shared__ __align__(16) short pbuf[4][16][32];
  f32x4 oacc[4];
#pragma unroll
  for (int d = 0; d < 4; ++d) oacc[d] = (f32x4){0.f, 0.f, 0.f, 0.f};
  for (int m0 = 0; m0 < N_; m0 += 32) {
#pragma unroll
    for (int cg = 0; cg < 2; ++cg) {
      const int mc = m0 + cg * 16;
      bf16x8 kf0 = load8f(kbp + (mc + l15) * D_ + lhi * 8);
      bf16x8 kf1 = load8f(kbp + (mc + l15) * D_ + 32 + lhi * 8);
      f32x4 acc = {0.f, 0.f, 0.f, 0.f};
      acc = __builtin_amdgcn_mfma_f32_16x16x32_bf16(qf0, kf0, acc, 0, 0, 0);
      acc = __builtin_amdgcn_mfma_f32_16x16x32_bf16(qf1, kf1, acc, 0, 0, 0);
      const float ic = 1.0f / csb[mc + l15];
#pragma unroll
      for (int r = 0; r < 4; ++r) {
        const int n = n0 + lhi * 4 + r;
        const float p = maskb[(size_t)n * N_ + mc + l15]
                            ? 0.f
                            : __expf(acc[r] * SCALE) * ic;
        pbuf[wave][lhi * 4 + r][cg * 16 + l15] = f2bf(p);
      }
    }
    __syncthreads();
    const bf16x8 pa =
        *reinterpret_cast<const bf16x8*>(&pbuf[wave][l15][lhi * 8]);
#pragma unroll
    for (int dsub = 0; dsub < 4; ++dsub) {
      bf16x8 vf;
#pragma unroll
      for (int j = 0; j < 8; ++j)
        vf[j] = f2bf(vbp[(m0 + lhi * 8 + j) * D_ + dsub * 16 + l15]);
      oacc[dsub] =
          __builtin_amdgcn_mfma_f32_16x16x32_bf16(pa, vf, oacc[dsub], 0, 0, 0);
    }
    __syncthreads();
  }
#pragma unroll
  for (int dsub = 0; dsub < 4; ++dsub)
#pragma unroll
    for (int r = 0; r < 4; ++r)
      out[(size_t)b * N_ * D_ + (size_t)(n0 + lhi * 4 + r) * D_ + dsub * 16 +
          l15] = oacc[dsub][r];
}

extern "C" void kernel_launch(void* const* d_in, const int* in_sizes, int n_in,
                              void* d_out, int out_size, void* d_ws,
                              size_t ws_size, hipStream_t stream) {
  const float* q = (const float*)d_in[0];
  const float* k = (const float*)d_in[1];
  const float* v = (const float*)d_in[2];
  const int* mask = (const int*)d_in[3];
  float* out = (float*)d_out;

  // workspace layout
  const size_t MB = 1024 * 1024;
  const size_t cs_off = 0;  // NCH*128 KB colsum partials
  const size_t qb_off = cs_off + NCH * (size_t)B_ * N_ * 4;  // 4 MB
  const size_t kb_off = qb_off + 4 * MB;
  const size_t vt_off = kb_off + 4 * MB;
  const size_t bt_off = vt_off + 4 * MB;  // 8 MB bitsT
  const size_t op_off = bt_off + 8 * MB;  // MCH*8 MB out partials
  const size_t need = op_off + (size_t)MCH * B_ * N_ * D_ * 4;

  if (ws_size >= need) {
    float* csp = (float*)((char*)d_ws + cs_off);
    short* qbf = (short*)((char*)d_ws + qb_off);
    short* kbf = (short*)((char*)d_ws + kb_off);
    short* vt = (short*)((char*)d_ws + vt_off);
    unsigned short* bitsT = (unsigned short*)((char*)d_ws + bt_off);
    float* outp = (float*)((char*)d_ws + op_off);

    cvt_bf16<<<dim3((B_ * N_ * D_) / (256 * 8), 2), 256, 0, stream>>>(
        q, k, qbf, kbf);
    colsum_pack<<<dim3(B_, N_ / 128, NCH), 256, 0, stream>>>(qbf, kbf, mask,
                                                             bitsT, csp);
    vprep_kernel<<<dim3(B_, N_ / 64), 256, 0, stream>>>(v, csp, vt);
    attn_out_kernel<<<dim3(B_, N_ / 64, MCH), 256, 0, stream>>>(qbf, kbf, vt,
                                                                bitsT, outp);
    reduce_out<<<(B_ * N_ * D_) / (256 * 4), 256, 0, stream>>>(outp, out);
  } else {
    float* colsum = (float*)d_ws;  // 128 KB
    colsum_fb<<<dim3(B_, N_ / 64), 256, 0, stream>>>(q, k, mask, colsum);
    attn_out_fb<<<dim3(B_, N_ / 64), 256, 0, stream>>>(q, k, v, mask, colsum,
                                                       out);
  }
}

// Round 6
// 496.794 us; speedup vs baseline: 1.1540x; 1.1540x over previous
//
#include <hip/hip_runtime.h>
#include <hip/hip_bf16.h>

// ScaledDotProductAttention: B=16, N=2048, D=64. q/k/v fp32, mask int32,
// out fp32. scores = q@k^T/sqrt(N); masked -> -1000; softmax over dim=1
// (COLUMN-wise over n); out = attn @ v.
// out[n,d] = sum_m exp(s[n,m])*[!mask] * (v[m,d]/colsum[m]).
//
// R6: materialize P (128 MB bf16) in A-fragment-ready layout instead of
// recomputing it in the PV pass (R3-R5 recompute kernels were latency-bound
// on scattered bits/kf loads). 5 dispatches:
//   1. cvt:    q,k fp32 -> bf16
//   2. score:  P tiles (exp, mask from RAW mask — coalesced, read once),
//              stored A-frag-ready; + colsum partials per 16-row group
//   3. vprep:  vt[b][d][m] = bf16(v[b][m][d] / colsum[b][m]) (fold partials)
//   4. pv:     out = P @ vt  — pure streaming MFMA GEMM, no LDS/barriers
//   5. reduce: sum MCH=2 partial outputs

#define B_ 16
#define N_ 2048
#define D_ 64
#define SCALE 0.022097086912079608f  // 1/sqrt(2048)
#define MCH 2                        // m-chunks for pv
#define SNCH 4                       // m-chunks for score kernel grid.z

typedef __attribute__((ext_vector_type(8))) short bf16x8;
typedef __attribute__((ext_vector_type(4))) float f32x4;

static __device__ __forceinline__ short f2bf(float x) {
  unsigned u = __float_as_uint(x);
  return (short)((u + 0x7FFF + ((u >> 16) & 1)) >> 16);
}

static __device__ __forceinline__ bf16x8 load8(const short* p) {
  return *reinterpret_cast<const bf16x8*>(p);
}

static __device__ __forceinline__ bf16x8 load8f(const float* p) {
  const f32x4 a = *reinterpret_cast<const f32x4*>(p);
  const f32x4 b = *reinterpret_cast<const f32x4*>(p + 4);
  bf16x8 r;
  r[0] = f2bf(a[0]); r[1] = f2bf(a[1]); r[2] = f2bf(a[2]); r[3] = f2bf(a[3]);
  r[4] = f2bf(b[0]); r[5] = f2bf(b[1]); r[6] = f2bf(b[2]); r[7] = f2bf(b[3]);
  return r;
}

// ---------------- 1. fp32 -> bf16 convert (q: y=0, k: y=1) ----------------
__global__ __launch_bounds__(256) void cvt_bf16(const float* __restrict__ q,
                                                const float* __restrict__ k,
                                                short* __restrict__ qb,
                                                short* __restrict__ kb) {
  const size_t i = ((size_t)blockIdx.x * 256 + threadIdx.x) * 8;
  const float* src = blockIdx.y ? k : q;
  short* dst = blockIdx.y ? kb : qb;
  *reinterpret_cast<bf16x8*>(dst + i) = load8f(src + i);
}

// ------- 2. score: P = exp(S)*!mask, stored A-fragment-ready + csp -------
// grid (B, N/64, SNCH); 4 waves/block; wave owns 16 n-rows, 512 m-cols.
// pstore layout: [b][n16][mi][lane][8] shorts, n16 = n0/16, mi = m0/32 —
// lane's PV A-fragment (A[n=l15][k=lhi*8+j]) is one contiguous 16B chunk;
// a wave's tile is 1 KB contiguous. csp[b][n16][m]: colsum over 16 rows.
__global__ __launch_bounds__(256) void score_kernel(
    const short* __restrict__ qb, const short* __restrict__ kb,
    const int* __restrict__ mask, short* __restrict__ pstore,
    float* __restrict__ csp) {
  const int b = blockIdx.x;
  const int wave = threadIdx.x >> 6;
  const int lane = threadIdx.x & 63;
  const int l15 = lane & 15;
  const int lhi = lane >> 4;
  const int n0 = blockIdx.y * 64 + wave * 16;
  const int n16 = blockIdx.y * 4 + wave;
  const int mbase = blockIdx.z * (N_ / SNCH);

  const short* qbb = qb + (size_t)b * N_ * D_;
  const short* kbb = kb + (size_t)b * N_ * D_;
  const int* maskb = mask + (size_t)b * N_ * N_;
  float* cspb = csp + ((size_t)b * 128 + n16) * N_;
  short* psb = pstore + (((size_t)b * 128 + n16) * 64) * 512;  // +mi*512

  const bf16x8 qf0 = load8(qbb + (n0 + l15) * D_ + lhi * 8);
  const bf16x8 qf1 = load8(qbb + (n0 + l15) * D_ + 32 + lhi * 8);

  __shared__ __align__(16) short pbuf[4][16][32];

  for (int m0 = mbase; m0 < mbase + N_ / SNCH; m0 += 32) {
    float colpart[2];
#pragma unroll
    for (int cg = 0; cg < 2; ++cg) {
      const int mc = m0 + cg * 16;
      const bf16x8 kf0 = load8(kbb + (mc + l15) * D_ + lhi * 8);
      const bf16x8 kf1 = load8(kbb + (mc + l15) * D_ + 32 + lhi * 8);
      f32x4 acc = {0.f, 0.f, 0.f, 0.f};
      acc = __builtin_amdgcn_mfma_f32_16x16x32_bf16(qf0, kf0, acc, 0, 0, 0);
      acc = __builtin_amdgcn_mfma_f32_16x16x32_bf16(qf1, kf1, acc, 0, 0, 0);
      float cp = 0.f;
#pragma unroll
      for (int r = 0; r < 4; ++r) {
        const int n = n0 + lhi * 4 + r;
        const int msk = maskb[(size_t)n * N_ + mc + l15];
        const float p = msk ? 0.f : __expf(acc[r] * SCALE);
        cp += p;
        pbuf[wave][lhi * 4 + r][cg * 16 + l15] = f2bf(p);
      }
      colpart[cg] = cp;
    }
    __syncthreads();
    // A-fragment: A[n=l15][k=lhi*8+j] = pbuf[wave][l15][lhi*8..+8] (16B).
    const bf16x8 pa =
        *reinterpret_cast<const bf16x8*>(&pbuf[wave][l15][lhi * 8]);
    *reinterpret_cast<bf16x8*>(psb + (size_t)(m0 >> 5) * 512 + lane * 8) = pa;
    // colsum over this wave's 16 rows: lanes {l15,+16,+32,+48} same column.
#pragma unroll
    for (int cg = 0; cg < 2; ++cg) {
      float p = colpart[cg];
      p += __shfl_xor(p, 16, 64);
      p += __shfl_xor(p, 32, 64);
      if (lane < 16) cspb[m0 + cg * 16 + l15] = p;
    }
    __syncthreads();
  }
}

// ------- 3. vt[b][d][m] = bf16(v[b][m][d] / sum_{n16} csp[b][n16][m]) -----
// grid (B, N/64); 64 m-columns per block.
__global__ __launch_bounds__(256) void vprep_kernel(
    const float* __restrict__ v, const float* __restrict__ csp,
    short* __restrict__ vt) {
  const int b = blockIdx.x;
  const int m0 = blockIdx.y * 64;
  const int tid = threadIdx.x;
  __shared__ float csl[4][64];
  __shared__ float cst[64];
  __shared__ float lds[64][65];

  // fold 128 partials: thread t sums quarter (t>>6) over cols m0+(t&63)
  {
    const int col = m0 + (tid & 63);
    const int q4 = tid >> 6;
    float s = 0.f;
    for (int j = 0; j < 32; ++j)
      s += csp[((size_t)b * 128 + q4 * 32 + j) * N_ + col];
    csl[q4][tid & 63] = s;
  }
  __syncthreads();
  if (tid < 64) cst[tid] = csl[0][tid] + csl[1][tid] + csl[2][tid] + csl[3][tid];
  __syncthreads();

  const float* vb = v + (size_t)b * N_ * D_;
#pragma unroll
  for (int pass = 0; pass < 4; ++pass) {
    const int mloc = pass * 16 + (tid >> 4);
    const int d4 = (tid & 15) * 4;
    const f32x4 x = *reinterpret_cast<const f32x4*>(vb + (m0 + mloc) * D_ + d4);
    const float ic = 1.0f / cst[mloc];
    lds[mloc][d4 + 0] = x[0] * ic;
    lds[mloc][d4 + 1] = x[1] * ic;
    lds[mloc][d4 + 2] = x[2] * ic;
    lds[mloc][d4 + 3] = x[3] * ic;
  }
  __syncthreads();
  const int d = tid >> 2;
  const int seg = tid & 3;
  bf16x8 o0, o1;
#pragma unroll
  for (int i = 0; i < 8; ++i) o0[i] = f2bf(lds[seg * 16 + i][d]);
#pragma unroll
  for (int i = 0; i < 8; ++i) o1[i] = f2bf(lds[seg * 16 + 8 + i][d]);
  short* dst = vt + (size_t)b * D_ * N_ + (size_t)d * N_ + m0 + seg * 16;
  *reinterpret_cast<bf16x8*>(dst) = o0;
  *reinterpret_cast<bf16x8*>(dst + 8) = o1;
}

// ------- 4. pv: outp[z] = P(:, mchunk z) @ vt(mchunk z, :) -------
// grid (B, N/64, MCH); pure streaming GEMM: 1 A-frag + 4 B-frag loads +
// 4 MFMA per iter; no LDS, no barriers.
__global__ __launch_bounds__(256) void pv_kernel(const short* __restrict__ pstore,
                                                 const short* __restrict__ vt,
                                                 float* __restrict__ outp) {
  const int b = blockIdx.x;
  const int wave = threadIdx.x >> 6;
  const int lane = threadIdx.x & 63;
  const int l15 = lane & 15;
  const int lhi = lane >> 4;
  const int n0 = blockIdx.y * 64 + wave * 16;
  const int n16 = blockIdx.y * 4 + wave;
  const int mibase = blockIdx.z * (64 / MCH);

  const short* psb =
      pstore + (((size_t)b * 128 + n16) * 64) * 512 + (size_t)lane * 8;
  const short* vtb = vt + (size_t)b * D_ * N_;

  f32x4 oacc[4];
#pragma unroll
  for (int d = 0; d < 4; ++d) oacc[d] = (f32x4){0.f, 0.f, 0.f, 0.f};

#pragma unroll 2
  for (int mi = mibase; mi < mibase + 64 / MCH; ++mi) {
    const bf16x8 pa = load8(psb + (size_t)mi * 512);
    const int m0 = mi * 32;
#pragma unroll
    for (int dsub = 0; dsub < 4; ++dsub) {
      const bf16x8 vf =
          load8(vtb + (size_t)(dsub * 16 + l15) * N_ + m0 + lhi * 8);
      oacc[dsub] =
          __builtin_amdgcn_mfma_f32_16x16x32_bf16(pa, vf, oacc[dsub], 0, 0, 0);
    }
  }

  float* dst = outp + (size_t)blockIdx.z * B_ * N_ * D_ + (size_t)b * N_ * D_;
#pragma unroll
  for (int dsub = 0; dsub < 4; ++dsub)
#pragma unroll
    for (int r = 0; r < 4; ++r)
      dst[(size_t)(n0 + lhi * 4 + r) * D_ + dsub * 16 + l15] = oacc[dsub][r];
}

// ---------------- 5. reduce the MCH partial outputs ----------------
__global__ __launch_bounds__(256) void reduce_out(const float* __restrict__ outp,
                                                  float* __restrict__ out) {
  const size_t i = ((size_t)blockIdx.x * 256 + threadIdx.x) * 4;
  f32x4 s = *reinterpret_cast<const f32x4*>(outp + i);
#pragma unroll
  for (int z = 1; z < MCH; ++z) {
    const f32x4 x =
        *reinterpret_cast<const f32x4*>(outp + (size_t)z * B_ * N_ * D_ + i);
    s[0] += x[0]; s[1] += x[1]; s[2] += x[2]; s[3] += x[3];
  }
  *reinterpret_cast<f32x4*>(out + i) = s;
}

// ================= R2 fallback (small-workspace path), verified ============
__global__ __launch_bounds__(256) void colsum_fb(
    const float* __restrict__ q, const float* __restrict__ k,
    const int* __restrict__ mask, float* __restrict__ colsum) {
  const int b = blockIdx.x;
  const int wave = threadIdx.x >> 6;
  const int lane = threadIdx.x & 63;
  const int l15 = lane & 15;
  const int lhi = lane >> 4;
  const int m0 = blockIdx.y * 64 + wave * 16;
  const float* qbp = q + (size_t)b * N_ * D_;
  const float* kbp = k + (size_t)b * N_ * D_;
  const int* maskb = mask + (size_t)b * N_ * N_;
  const bf16x8 kf0 = load8f(kbp + (m0 + l15) * D_ + lhi * 8);
  const bf16x8 kf1 = load8f(kbp + (m0 + l15) * D_ + 32 + lhi * 8);
  float partial = 0.f;
  for (int n0 = 0; n0 < N_; n0 += 16) {
    bf16x8 qf0 = load8f(qbp + (n0 + l15) * D_ + lhi * 8);
    bf16x8 qf1 = load8f(qbp + (n0 + l15) * D_ + 32 + lhi * 8);
    f32x4 acc = {0.f, 0.f, 0.f, 0.f};
    acc = __builtin_amdgcn_mfma_f32_16x16x32_bf16(qf0, kf0, acc, 0, 0, 0);
    acc = __builtin_amdgcn_mfma_f32_16x16x32_bf16(qf1, kf1, acc, 0, 0, 0);
#pragma unroll
    for (int r = 0; r < 4; ++r) {
      const int n = n0 + lhi * 4 + r;
      partial +=
          maskb[(size_t)n * N_ + m0 + l15] ? 0.f : __expf(acc[r] * SCALE);
    }
  }
  partial += __shfl_xor(partial, 16, 64);
  partial += __shfl_xor(partial, 32, 64);
  if (lane < 16) colsum[(size_t)b * N_ + m0 + l15] = partial;
}

__global__ __launch_bounds__(256) void attn_out_fb(
    const float* __restrict__ q, const float* __restrict__ k,
    const float* __restrict__ v, const int* __restrict__ mask,
    const float* __restrict__ colsum, float* __restrict__ out) {
  const int b = blockIdx.x;
  const int wave = threadIdx.x >> 6;
  const int lane = threadIdx.x & 63;
  const int l15 = lane & 15;
  const int lhi = lane >> 4;
  const int n0 = blockIdx.y * 64 + wave * 16;
  const float* qbp = q + (size_t)b * N_ * D_;
  const float* kbp = k + (size_t)b * N_ * D_;
  const float* vbp = v + (size_t)b * N_ * D_;
  const int* maskb = mask + (size_t)b * N_ * N_;
  const float* csb = colsum + (size_t)b * N_;
  const bf16x8 qf0 = load8f(qbp + (n0 + l15) * D_ + lhi * 8);
  const bf16x8 qf1 = load8f(qbp + (n0 + l15) * D_ + 32 + lhi * 8);
  __shared__ __align__(16) short pbuf[4][16][32];
  f32x4 oacc[4];
#pragma unroll
  for (int d = 0; d < 4; ++d) oacc[d] = (f32x4){0.f, 0.f, 0.f, 0.f};
  for (int m0 = 0; m0 < N_; m0 += 32) {
#pragma unroll
    for (int cg = 0; cg < 2; ++cg) {
      const int mc = m0 + cg * 16;
      bf16x8 kf0 = load8f(kbp + (mc + l15) * D_ + lhi * 8);
      bf16x8 kf1 = load8f(kbp + (mc + l15) * D_ + 32 + lhi * 8);
      f32x4 acc = {0.f, 0.f, 0.f, 0.f};
      acc = __builtin_amdgcn_mfma_f32_16x16x32_bf16(qf0, kf0, acc, 0, 0, 0);
      acc = __builtin_amdgcn_mfma_f32_16x16x32_bf16(qf1, kf1, acc, 0, 0, 0);
      const float ic = 1.0f / csb[mc + l15];
#pragma unroll
      for (int r = 0; r < 4; ++r) {
        const int n = n0 + lhi * 4 + r;
        const float p = maskb[(size_t)n * N_ + mc + l15]
                            ? 0.f
                            : __expf(acc[r] * SCALE) * ic;
        pbuf[wave][lhi * 4 + r][cg * 16 + l15] = f2bf(p);
      }
    }
    __syncthreads();
    const bf16x8 pa =
        *reinterpret_cast<const bf16x8*>(&pbuf[wave][l15][lhi * 8]);
#pragma unroll
    for (int dsub = 0; dsub < 4; ++dsub) {
      bf16x8 vf;
#pragma unroll
      for (int j = 0; j < 8; ++j)
        vf[j] = f2bf(vbp[(m0 + lhi * 8 + j) * D_ + dsub * 16 + l15]);
      oacc[dsub] =
          __builtin_amdgcn_mfma_f32_16x16x32_bf16(pa, vf, oacc[dsub], 0, 0, 0);
    }
    __syncthreads();
  }
#pragma unroll
  for (int dsub = 0; dsub < 4; ++dsub)
#pragma unroll
    for (int r = 0; r < 4; ++r)
      out[(size_t)b * N_ * D_ + (size_t)(n0 + lhi * 4 + r) * D_ + dsub * 16 +
          l15] = oacc[dsub][r];
}

extern "C" void kernel_launch(void* const* d_in, const int* in_sizes, int n_in,
                              void* d_out, int out_size, void* d_ws,
                              size_t ws_size, hipStream_t stream) {
  const float* q = (const float*)d_in[0];
  const float* k = (const float*)d_in[1];
  const float* v = (const float*)d_in[2];
  const int* mask = (const int*)d_in[3];
  float* out = (float*)d_out;

  // workspace layout
  const size_t MB = 1024 * 1024;
  const size_t qb_off = 0;                 // 4 MB qbf
  const size_t kb_off = qb_off + 4 * MB;   // 4 MB kbf
  const size_t vt_off = kb_off + 4 * MB;   // 4 MB vt
  const size_t cs_off = vt_off + 4 * MB;   // 16 MB csp (128 partials)
  const size_t ps_off = cs_off + 16 * MB;  // 128 MB pstore
  const size_t op_off = ps_off + 128 * MB; // MCH*8 MB out partials
  const size_t need = op_off + (size_t)MCH * B_ * N_ * D_ * 4;

  if (ws_size >= need) {
    short* qbf = (short*)((char*)d_ws + qb_off);
    short* kbf = (short*)((char*)d_ws + kb_off);
    short* vt = (short*)((char*)d_ws + vt_off);
    float* csp = (float*)((char*)d_ws + cs_off);
    short* pstore = (short*)((char*)d_ws + ps_off);
    float* outp = (float*)((char*)d_ws + op_off);

    cvt_bf16<<<dim3((B_ * N_ * D_) / (256 * 8), 2), 256, 0, stream>>>(
        q, k, qbf, kbf);
    score_kernel<<<dim3(B_, N_ / 64, SNCH), 256, 0, stream>>>(qbf, kbf, mask,
                                                              pstore, csp);
    vprep_kernel<<<dim3(B_, N_ / 64), 256, 0, stream>>>(v, csp, vt);
    pv_kernel<<<dim3(B_, N_ / 64, MCH), 256, 0, stream>>>(pstore, vt, outp);
    reduce_out<<<(B_ * N_ * D_) / (256 * 4), 256, 0, stream>>>(outp, out);
  } else {
    float* colsum = (float*)d_ws;  // 128 KB
    colsum_fb<<<dim3(B_, N_ / 64), 256, 0, stream>>>(q, k, mask, colsum);
    attn_out_fb<<<dim3(B_, N_ / 64), 256, 0, stream>>>(q, k, v, mask, colsum,
                                                       out);
  }
}